// Round 14
// baseline (141.331 us; speedup 1.0000x reference)
//
#include <hip/hip_runtime.h>
#include <math.h>

#define SIGMA_BOOST 2.0f
#define EPSILON 1e-6f

// native clang vector type (required for nontemporal builtins and "+v" pins)
typedef float vfloat4 __attribute__((ext_vector_type(4)));

// value pin: load feeding v cannot be sunk past this point (zero cost)
#define PIN4(v)  asm volatile("" : "+v"(v))

// ---------------------------------------------------------------------------
// Pre-pass: per-t parameters -> float4 {mean_row, mean_col, sigma, pvalue}
//   mean  = sigmoid(pmean) * (N-1)
//   sigma = (softplus(psigma + SIGMA_BOOST) + EPS) * N
// ---------------------------------------------------------------------------
__global__ void params_kernel(const float2* __restrict__ pmeans,
                              const float* __restrict__ psigmas,
                              const float* __restrict__ pvalues,
                              float4* __restrict__ params, int N) {
    int t = blockIdx.x * blockDim.x + threadIdx.x;
    if (t >= N) return;
    float2 pm = pmeans[t];
    float scale = (float)(N - 1);
    float m0 = __fmul_rn(__fdiv_rn(1.0f, __fadd_rn(1.0f, expf(-pm.x))), scale);
    float m1 = __fmul_rn(__fdiv_rn(1.0f, __fadd_rn(1.0f, expf(-pm.y))), scale);
    float z  = __fadd_rn(psigmas[t], SIGMA_BOOST);
    float sp = __fadd_rn(fmaxf(z, 0.0f), log1pf(expf(-fabsf(z))));
    float sg = __fmul_rn(__fadd_rn(sp, EPSILON), (float)N);
    params[t] = make_float4(m0, m1, sg, pvalues[t]);
}

// ---------------------------------------------------------------------------
// Round 14 — tune the r13 winner (x+y in LDS; gather on lgkmcnt; masked LDS
// atomics + 0/N-1 register peel). r13 dropped contract below the top-5
// (total 147.9 -> 140.3us) confirming the vmcnt-domain diagnosis. This round:
//   - 4 samples per step (steps 8 -> 4): more ds_read/atomic ILP per commit,
//     half the loop overhead. VGPR budget is 128 now (launch_bounds(1024,4))
//     so hipcc has no pressure to sink the prefetch.
//   - prologue stream loads issued BEFORE the x-staging loop: the 64 KB
//     coalesced stage overlaps the first step's HBM latency for free.
//   - fast-path flag passed from host (r13 latent bug: kernel couldn't see
//     whether the 128 KB dynamic-LDS grant succeeded).
// Numerics bit-identical to the verified kernels.
// ---------------------------------------------------------------------------
template <bool INLINE_PARAMS>
__launch_bounds__(1024, 4)
__global__ void contract_kernel(const float* __restrict__ x,
                                const float2* __restrict__ noise,
                                const float4* __restrict__ params,
                                const float2* __restrict__ pmeans,
                                const float* __restrict__ psigmas,
                                const float* __restrict__ pvalues,
                                float* __restrict__ y, int N, int fast_flag) {
    extern __shared__ float lds[];
    float* ly = lds;          // N floats: y-row accumulator
    float* lx = lds + N;      // N floats: x-row copy (fast path only)
    const int b = blockIdx.x;
    const int tid = threadIdx.x;
    const int nthr = blockDim.x;

    const float* xb = x + (size_t)b * N;
    const float fN1 = (float)(N - 1);
    const int iN1 = N - 1;
    const int n4 = N >> 2;

    const int npairs = N >> 1;
    const int steps4 = (npairs % (2 * nthr) == 0) ? npairs / (2 * nthr) : 0;
    const bool fast = fast_flag && !INLINE_PARAMS && steps4 >= 1 &&
                      ((N & 3) == 0);

    float acc0 = 0.0f, accE = 0.0f;
    float4* ly4 = (float4*)ly;

    if (fast) {
        const vfloat4* nb4 = (const vfloat4*)(noise + (size_t)b * N); // N/2
        const vfloat4* pp  = (const vfloat4*)params;

        // ---- prologue: issue step-0's stream loads FIRST (overlap stage) ---
        int q0 = tid, q1 = tid + nthr;
        vfloat4 nzA = __builtin_nontemporal_load(&nb4[q0]);
        vfloat4 nzB = __builtin_nontemporal_load(&nb4[q1]);
        vfloat4 pa = pp[2 * q0];
        vfloat4 pb = pp[2 * q0 + 1];
        vfloat4 pc = pp[2 * q1];
        vfloat4 pd = pp[2 * q1 + 1];
        PIN4(nzA); PIN4(nzB); PIN4(pa); PIN4(pb); PIN4(pc); PIN4(pd);

        // ---- stage x-row into LDS, zero y accumulator ----------------------
        {
            vfloat4* lx4 = (vfloat4*)lx;
            const vfloat4* xb4 = (const vfloat4*)xb;
            for (int i = tid; i < n4; i += nthr) {
                ly4[i] = make_float4(0.f, 0.f, 0.f, 0.f);
                lx4[i] = xb4[i];
            }
        }
        __syncthreads();

        for (int s = 0; s < steps4; ++s) {
            // ---- zone A: 8 indices from current regs; 4 LDS gathers --------
            // sample = mean + sigma*noise, deliberately UNFUSED (numpy match)
            float sA0 = __fadd_rn(pa.x, __fmul_rn(pa.z, nzA.x));
            float sA1 = __fadd_rn(pa.y, __fmul_rn(pa.z, nzA.y));
            float sB0 = __fadd_rn(pb.x, __fmul_rn(pb.z, nzA.z));
            float sB1 = __fadd_rn(pb.y, __fmul_rn(pb.z, nzA.w));
            float sC0 = __fadd_rn(pc.x, __fmul_rn(pc.z, nzB.x));
            float sC1 = __fadd_rn(pc.y, __fmul_rn(pc.z, nzB.y));
            float sD0 = __fadd_rn(pd.x, __fmul_rn(pd.z, nzB.z));
            float sD1 = __fadd_rn(pd.y, __fmul_rn(pd.z, nzB.w));
            // np.round = half-to-even = rintf; clamp in float, exact int cvt
            int rA = (int)fminf(fmaxf(rintf(sA0), 0.0f), fN1);
            int cA = (int)fminf(fmaxf(rintf(sA1), 0.0f), fN1);
            int rB = (int)fminf(fmaxf(rintf(sB0), 0.0f), fN1);
            int cB = (int)fminf(fmaxf(rintf(sB1), 0.0f), fN1);
            int rC = (int)fminf(fmaxf(rintf(sC0), 0.0f), fN1);
            int cC = (int)fminf(fmaxf(rintf(sC1), 0.0f), fN1);
            int rD = (int)fminf(fmaxf(rintf(sD0), 0.0f), fN1);
            int cD = (int)fminf(fmaxf(rintf(sD1), 0.0f), fN1);
            float wA = pa.w, wB = pb.w, wC = pc.w, wD = pd.w;
            float xvA = lx[cA];              // ds_read_b32 (lgkmcnt domain)
            float xvB = lx[cB];
            float xvC = lx[cC];
            float xvD = lx[cD];

            // ---- zone B: prefetch next step's stream set (vmcnt domain) ----
            vfloat4 nzAn, nzBn, pan, pbn, pcn, pdn;
            bool have_next = (s + 1 < steps4);
            if (have_next) {                 // uniform branch
                int q0n = q0 + 2 * nthr, q1n = q1 + 2 * nthr;
                nzAn = __builtin_nontemporal_load(&nb4[q0n]);
                nzBn = __builtin_nontemporal_load(&nb4[q1n]);
                pan = pp[2 * q0n];
                pbn = pp[2 * q0n + 1];
                pcn = pp[2 * q1n];
                pdn = pp[2 * q1n + 1];
                PIN4(nzAn); PIN4(nzBn); PIN4(pan); PIN4(pbn); PIN4(pcn); PIN4(pdn);
                q0 = q0n; q1 = q1n;
            }

            // ---- zone C: commit — waits lgkmcnt only; vmcnt stays loaded ---
            float ctrA = __fmul_rn(wA, xvA);
            float ctrB = __fmul_rn(wB, xvB);
            float ctrC = __fmul_rn(wC, xvC);
            float ctrD = __fmul_rn(wD, xvD);
            bool loA = (rA == 0), hiA = (rA == iN1);
            bool loB = (rB == 0), hiB = (rB == iN1);
            bool loC = (rC == 0), hiC = (rC == iN1);
            bool loD = (rD == 0), hiD = (rD == iN1);
            if (!(loA | hiA)) atomicAdd(&ly[rA], ctrA);   // ~20% lanes active
            if (!(loB | hiB)) atomicAdd(&ly[rB], ctrB);
            if (!(loC | hiC)) atomicAdd(&ly[rC], ctrC);
            if (!(loD | hiD)) atomicAdd(&ly[rD], ctrD);
            acc0 = __fadd_rn(acc0, loA ? ctrA : 0.0f);    // cndmask, branchless
            accE = __fadd_rn(accE, hiA ? ctrA : 0.0f);
            acc0 = __fadd_rn(acc0, loB ? ctrB : 0.0f);
            accE = __fadd_rn(accE, hiB ? ctrB : 0.0f);
            acc0 = __fadd_rn(acc0, loC ? ctrC : 0.0f);
            accE = __fadd_rn(accE, hiC ? ctrC : 0.0f);
            acc0 = __fadd_rn(acc0, loD ? ctrD : 0.0f);
            accE = __fadd_rn(accE, hiD ? ctrD : 0.0f);

            if (have_next) {
                nzA = nzAn; nzB = nzBn; pa = pan; pb = pbn; pc = pcn; pd = pdn;
            }
        }
    } else {
        // ---- generic / inline-params fallback (r6-verified masked body) ----
        for (int i = tid; i < n4; i += nthr)
            ly4[i] = make_float4(0.f, 0.f, 0.f, 0.f);
        __syncthreads();
        const float2* nb = noise + (size_t)b * N;
        for (int t = tid; t < N; t += nthr) {
            float4 p;
            if (INLINE_PARAMS) {
                float2 pm = pmeans[t];
                float scale = (float)(N - 1);
                p.x = __fmul_rn(__fdiv_rn(1.0f, __fadd_rn(1.0f, expf(-pm.x))), scale);
                p.y = __fmul_rn(__fdiv_rn(1.0f, __fadd_rn(1.0f, expf(-pm.y))), scale);
                float z  = __fadd_rn(psigmas[t], SIGMA_BOOST);
                float sp = __fadd_rn(fmaxf(z, 0.0f), log1pf(expf(-fabsf(z))));
                p.z = __fmul_rn(__fadd_rn(sp, EPSILON), (float)N);
                p.w = pvalues[t];
            } else {
                p = ((const float4*)params)[t];
            }
            float2 nz = nb[t];
            float s0 = __fadd_rn(p.x, __fmul_rn(p.z, nz.x));
            float s1 = __fadd_rn(p.y, __fmul_rn(p.z, nz.y));
            int row = (int)fminf(fmaxf(rintf(s0), 0.0f), fN1);
            int col = (int)fminf(fmaxf(rintf(s1), 0.0f), fN1);
            float xv = xb[col];
            float ctr = __fmul_rn(p.w, xv);
            bool lo = (row == 0);
            bool hi = (row == iN1);
            if (!(lo | hi)) atomicAdd(&ly[row], ctr);
            acc0 = __fadd_rn(acc0, lo ? ctr : 0.0f);
            accE = __fadd_rn(accE, hi ? ctr : 0.0f);
        }
    }

    // fold register accumulators: wave shfl-reduce, one atomic per wave
    for (int off = 32; off > 0; off >>= 1) {
        acc0 = __fadd_rn(acc0, __shfl_down(acc0, off, 64));
        accE = __fadd_rn(accE, __shfl_down(accE, off, 64));
    }
    if ((tid & 63) == 0) {
        atomicAdd(&ly[0], acc0);
        atomicAdd(&ly[iN1], accE);
    }
    __syncthreads();

    // coalesced nontemporal write-out of the full row (y is never re-read)
    const vfloat4* lv4 = (const vfloat4*)ly;
    vfloat4* yb4 = (vfloat4*)(y + (size_t)b * N);
    for (int i = tid; i < n4; i += nthr)
        __builtin_nontemporal_store(lv4[i], &yb4[i]);
}

extern "C" void kernel_launch(void* const* d_in, const int* in_sizes, int n_in,
                              void* d_out, int out_size, void* d_ws, size_t ws_size,
                              hipStream_t stream) {
    const float*  x       = (const float*)d_in[0];
    const float2* noise   = (const float2*)d_in[1];
    const float2* pmeans  = (const float2*)d_in[2];
    const float*  psigmas = (const float*)d_in[3];
    const float*  pvalues = (const float*)d_in[4];
    float* y = (float*)d_out;

    const int N = in_sizes[3];          // psigmas is (N,)
    const int B = in_sizes[0] / N;      // x is (B,N)

    const size_t params_bytes = (size_t)N * sizeof(float4);
    const bool use_ws = (ws_size >= params_bytes) && (d_ws != nullptr);

    const int block = 1024;
    const size_t lds_min  = (size_t)N * sizeof(float);       // 64 KB: ly only
    const size_t lds_fast = 2 * lds_min;                     // 128 KB: ly + lx

    // fast-path shape gate (mirrors the kernel's condition)
    const bool shape_ok = ((N >> 1) % (2 * block) == 0) && ((N & 3) == 0) &&
                          lds_fast <= 160 * 1024;

    if (use_ws) {
        bool fast_ok = shape_ok;
        if (fast_ok) {
            // dynamic LDS >64KB needs the opt-in attribute (verified r3/r13)
            hipError_t e = hipFuncSetAttribute(
                reinterpret_cast<const void*>(&contract_kernel<false>),
                hipFuncAttributeMaxDynamicSharedMemorySize, (int)lds_fast);
            fast_ok = (e == hipSuccess);
        }
        float4* params = (float4*)d_ws;
        params_kernel<<<(N + 255) / 256, 256, 0, stream>>>(pmeans, psigmas,
                                                           pvalues, params, N);
        contract_kernel<false><<<B, block,
                                 fast_ok ? lds_fast : lds_min, stream>>>(
            x, noise, params, nullptr, nullptr, nullptr, y, N,
            fast_ok ? 1 : 0);
    } else {
        contract_kernel<true><<<B, block, lds_min, stream>>>(
            x, noise, nullptr, pmeans, psigmas, pvalues, y, N, 0);
    }
}